// Round 16
// baseline (94.252 us; speedup 1.0000x reference)
//
#include <hip/hip_runtime.h>
#include <hip/hip_bf16.h>

typedef __bf16 bf16_t;
typedef __bf16 bf16x8 __attribute__((ext_vector_type(8)));
typedef __bf16 bf16x4 __attribute__((ext_vector_type(4)));
typedef float f32x4 __attribute__((ext_vector_type(4)));
typedef unsigned int u32;

#define D_MODEL 1024
#define T_SEQ   2048
#define N_HEADS 16

#define WAITVM(N) asm volatile("s_waitcnt vmcnt(" #N ")" ::: "memory")

__device__ __forceinline__ void gload_lds16(const void* g, void* l) {
  __builtin_amdgcn_global_load_lds((const __attribute__((address_space(1))) u32*)g,
                                   (__attribute__((address_space(3))) u32*)l, 16, 0, 0);
}

__device__ __forceinline__ float fast_exp2(float x) {
#if __has_builtin(__builtin_amdgcn_exp2f)
  return __builtin_amdgcn_exp2f(x);
#else
  return __expf(x * 0.69314718056f);
#endif
}

// ---------------- fused fp32->bf16 cast (x + 4 weights), 8 elems/thread ------
struct CastArgs { const float* src[5]; bf16_t* dst[5]; };

__global__ __launch_bounds__(256) void cast_all(CastArgs p) {
  unsigned i = (blockIdx.x * 256u + threadIdx.x) * 8u;
  int seg; unsigned off;
  if (i < 4194304u) { seg = 0; off = i; }
  else { unsigned r = i - 4194304u; seg = 1 + (int)(r >> 20); off = r & 1048575u; }
  const float4 v0 = *(const float4*)(p.src[seg] + off);
  const float4 v1 = *(const float4*)(p.src[seg] + off + 4);
  bf16x8 o = { (bf16_t)v0.x, (bf16_t)v0.y, (bf16_t)v0.z, (bf16_t)v0.w,
               (bf16_t)v1.x, (bf16_t)v1.y, (bf16_t)v1.z, (bf16_t)v1.w };
  *(bf16x8*)(p.dst[seg] + off) = o;
}

#define QSCL 0.18033688011112042f   // 0.125 * log2(e)

// ============== fused QKV: 128x192 tile, BK=64, 256 thr, 2 blocks/CU =========
struct QKVArgs {
  const bf16_t* A;
  const bf16_t* W[3];
  const float* bias[3];
  bf16_t* out[3];
};

__global__ __launch_bounds__(256, 2) void qkv_gemm(QKVArgs p) {
  __shared__ bf16_t lds[2 * 20480];   // [buf][A:8192 | B:12288] elems

  const int tid = threadIdx.x;
  const int l = tid & 63, w = tid >> 6;
  const int lh = l >> 4, r15 = l & 15;

  const int lid = blockIdx.x;
  const int by = lid & 15, bx = lid >> 4;
  const int brow = bx * 128;
  const int gcol0 = by * 192;

  const int wr = (w >> 1) * 64;
  const int wc = (w & 1) * 96;
  const int wrc = wr >> 4;
  const int wcc = wc >> 4;
  const int sA = (lh ^ ((r15 >> 1) & 3)) * 8;
  const int roff = r15 * 32;

  const int srow = l >> 2;
  const int gs = ((l & 3) ^ ((l >> 3) & 3)) * 8;

  f32x4 acc[4][6];
  const f32x4 zero = {0.f, 0.f, 0.f, 0.f};
#pragma unroll
  for (int i = 0; i < 4; ++i)
#pragma unroll
    for (int j = 0; j < 6; ++j) acc[i][j] = zero;

  const bf16_t* A = p.A;

  auto stage = [&](bf16_t* buf, int k0) {
#pragma unroll
    for (int i = 0; i < 4; ++i) {
      int c = w * 4 + i;
      int kh = c >> 3, cc = c & 7;
      gload_lds16(A + (size_t)(brow + cc * 16 + srow) * D_MODEL + k0 + kh * 32 + gs,
                  buf + c * 512);
    }
#pragma unroll
    for (int i = 0; i < 6; ++i) {
      int g = w * 6 + i;
      int kh = g >= 12;
      int cb = g - kh * 12;
      int gcol = gcol0 + cb * 16 + srow;
      int z = gcol >> 10;
      const bf16_t* wt = (z == 0) ? p.W[0] : ((z == 1) ? p.W[1] : p.W[2]);
      gload_lds16(wt + (size_t)(gcol & 1023) * D_MODEL + k0 + kh * 32 + gs,
                  buf + 8192 + g * 512);
    }
  };

  stage(lds, 0);

  for (int t = 0; t < 16; ++t) {
    bf16_t* cur = lds + (t & 1) * 20480;
    WAITVM(0);
    __builtin_amdgcn_s_barrier();
    if (t < 15) stage(lds + ((t + 1) & 1) * 20480, (t + 1) * 64);

#pragma unroll
    for (int kh = 0; kh < 2; ++kh) {
      bf16x8 bfr[6];
#pragma unroll
      for (int ni = 0; ni < 6; ++ni)
        bfr[ni] = *(const bf16x8*)(cur + 8192 + (kh * 12 + wcc + ni) * 512 + roff + sA);
      __builtin_amdgcn_s_setprio(1);
#pragma unroll
      for (int mi = 0; mi < 4; ++mi) {
        bf16x8 af = *(const bf16x8*)(cur + (kh * 8 + wrc + mi) * 512 + roff + sA);
#pragma unroll
        for (int ni = 0; ni < 6; ++ni)
          acc[mi][ni] = __builtin_amdgcn_mfma_f32_16x16x32_bf16(af, bfr[ni], acc[mi][ni], 0, 0, 0);
      }
      __builtin_amdgcn_s_setprio(0);
    }
  }

#pragma unroll
  for (int ni = 0; ni < 6; ++ni) {
    const int col = gcol0 + wc + ni * 16 + r15;
    const int z = col >> 10;
    const int zc = col & 1023;
    const float* bias = (z == 0) ? p.bias[0] : ((z == 1) ? p.bias[1] : p.bias[2]);
    bf16_t* O = (z == 0) ? p.out[0] : ((z == 1) ? p.out[1] : p.out[2]);
    const float bz = bias[zc];
    if (z == 2) {
#pragma unroll
      for (int mi = 0; mi < 4; ++mi) {
        int row0 = brow + wr + mi * 16 + lh * 4;
        int bb = row0 >> 11, t0 = row0 & 2047;
        bf16x4 pk;
#pragma unroll
        for (int j = 0; j < 4; ++j) pk[j] = (bf16_t)(acc[mi][ni][j] + bz);
        *(bf16x4*)(O + (size_t)bb * (D_MODEL * T_SEQ) + (size_t)zc * T_SEQ + t0) = pk;
      }
    } else if (z == 0) {
#pragma unroll
      for (int mi = 0; mi < 4; ++mi) {
        int row0 = brow + wr + mi * 16 + lh * 4;
#pragma unroll
        for (int j = 0; j < 4; ++j)
          O[(size_t)(row0 + j) * D_MODEL + zc] = (bf16_t)((acc[mi][ni][j] + bz) * QSCL);
      }
    } else {
#pragma unroll
      for (int mi = 0; mi < 4; ++mi) {
        int row0 = brow + wr + mi * 16 + lh * 4;
#pragma unroll
        for (int j = 0; j < 4; ++j)
          O[(size_t)(row0 + j) * D_MODEL + zc] = (bf16_t)(acc[mi][ni][j] + bz);
      }
    }
  }
}

// ---------------- out projection: 64x128 tile, R14 handshake ----------------
__global__ __launch_bounds__(256, 2) void out_gemm(
    const bf16_t* __restrict__ A, const bf16_t* __restrict__ W,
    const float* __restrict__ bias, float* __restrict__ O)
{
  __shared__ bf16_t lds[2 * 12288];

  const int tid = threadIdx.x;
  const int l = tid & 63, w = tid >> 6;
  const int lh = l >> 4, r15 = l & 15;

  const int brow = blockIdx.x * 64, bcol = blockIdx.y * 128;
  const int wr = (w >> 1) * 32;
  const int wc = (w & 1) * 64;
  const int wrc = wr >> 4;
  const int wcc = wc >> 4;
  const int sA = (lh ^ ((r15 >> 1) & 3)) * 8;
  const int roff = r15 * 32;

  const int srow = l >> 2;
  const int gs = ((l & 3) ^ ((l >> 3) & 3)) * 8;

  f32x4 acc[2][4];
  const f32x4 zero = {0.f, 0.f, 0.f, 0.f};
#pragma unroll
  for (int i = 0; i < 2; ++i)
#pragma unroll
    for (int j = 0; j < 4; ++j) acc[i][j] = zero;

  auto stage = [&](bf16_t* buf, int k0) {
#pragma unroll
    for (int i = 0; i < 2; ++i) {
      int c = w * 2 + i;
      int kh = c >> 2, cc = c & 3;
      gload_lds16(A + (size_t)(brow + cc * 16 + srow) * D_MODEL + k0 + kh * 32 + gs,
                  buf + c * 512);
    }
#pragma unroll
    for (int i = 0; i < 4; ++i) {
      int g = w * 4 + i;
      int kh = g >> 3, cb = g & 7;
      gload_lds16(W + (size_t)(bcol + cb * 16 + srow) * D_MODEL + k0 + kh * 32 + gs,
                  buf + 4096 + g * 512);
    }
  };

  stage(lds, 0);

  for (int t = 0; t < 16; ++t) {
    bf16_t* cur = lds + (t & 1) * 12288;
    WAITVM(0);
    __builtin_amdgcn_s_barrier();
    if (t < 15) stage(lds + ((t + 1) & 1) * 12288, (t + 1) * 64);

#pragma unroll
    for (int kh = 0; kh < 2; ++kh) {
      bf16x8 bfr[4];
#pragma unroll
      for (int ni = 0; ni < 4; ++ni)
        bfr[ni] = *(const bf16x8*)(cur + 4096 + (kh * 8 + wcc + ni) * 512 + roff + sA);
      __builtin_amdgcn_s_setprio(1);
#pragma unroll
      for (int mi = 0; mi < 2; ++mi) {
        bf16x8 af = *(const bf16x8*)(cur + (kh * 4 + wrc + mi) * 512 + roff + sA);
#pragma unroll
        for (int ni = 0; ni < 4; ++ni)
          acc[mi][ni] = __builtin_amdgcn_mfma_f32_16x16x32_bf16(af, bfr[ni], acc[mi][ni], 0, 0, 0);
      }
      __builtin_amdgcn_s_setprio(0);
    }
  }

#pragma unroll
  for (int ni = 0; ni < 4; ++ni) {
    int col = bcol + wc + ni * 16 + r15;
    float bz = bias[col];
#pragma unroll
    for (int mi = 0; mi < 2; ++mi) {
      int row0 = brow + wr + mi * 16 + lh * 4;
#pragma unroll
      for (int j = 0; j < 4; ++j)
        O[(size_t)(row0 + j) * D_MODEL + col] = acc[mi][ni][j] + bz;
    }
  }
}

// ---------------- causal flash attention: folded-uniform, KVBLK=128 ----------
// 512 blocks, each = q-tiles {pair, 31-pair} run sequentially = exactly 17
// kv-tile-units -> all blocks equal length, 2 resident/CU for the whole kernel.
// Body = R13/R15 proven handshake (2 barriers/tile, pre-covered vmcnt(0)).
__device__ __forceinline__ void stage_k128(const bf16_t* Kg, bf16_t* Kd, int kv0, int w, int l) {
#pragma unroll
  for (int i = 0; i < 4; ++i) {
    int c = w * 4 + i;
    int row = c * 8 + (l >> 3);
    int gcol = ((l & 7) ^ ((l >> 3) & 7)) * 8;
    gload_lds16(Kg + (size_t)(kv0 + row) * D_MODEL + gcol, Kd + c * 512);
  }
}
__device__ __forceinline__ void stage_v128(const bf16_t* Vg, bf16_t* Vd, int kv0, int w, int l) {
#pragma unroll
  for (int i = 0; i < 4; ++i) {
    int c = w * 4 + i;
    int drow = c * 4 + (l >> 4);
    int gkv = ((l & 15) ^ (drow & 15)) * 8;
    gload_lds16(Vg + (size_t)drow * T_SEQ + kv0 + gkv, Vd + c * 512);
  }
}

__global__ __launch_bounds__(256) void flash_attn(
    const bf16_t* __restrict__ Qm, const bf16_t* __restrict__ Km,
    const bf16_t* __restrict__ Vtg, bf16_t* __restrict__ Om)
{
  __shared__ bf16_t Kls[128 * 64];
  __shared__ bf16_t Vls[64 * 128];
  __shared__ bf16_t Pls[4][16 * 64];

  const int tid = threadIdx.x, l = tid & 63, w = tid >> 6;
  const int lh = l >> 4, r15 = l & 15;

  const int lid = blockIdx.x;
  const int pair = lid >> 5;            // 0..15
  const int bh = lid & 31;              // head pinned to one XCD
  const int b = bh >> 4, h = bh & 15;
  const int qtA = 31 - pair;            // big chain first
  const int qtB = pair;
  const int nA = (qtA >> 1) + 1;
  const int NT = 17;                    // uniform across all blocks

  const size_t baseQ = (size_t)b * T_SEQ * D_MODEL + h * 64;
  const size_t baseVt = (size_t)b * (D_MODEL * T_SEQ) + (size_t)(h * 64) * T_SEQ;
  const bf16_t* Kg = Km + baseQ;
  const bf16_t* Vg = Vtg + baseVt;
  const int sw7 = r15 & 7;

  int qt = qtA;
  int nTc = nA;                         // tiles in current chain
  int qw = qt * 64 + w * 16;
  int qrow = qw + r15;

  bf16x8 qf[2];
  {
    const bf16_t* qp = Qm + baseQ + (size_t)qrow * D_MODEL + lh * 8;
    qf[0] = *(const bf16x8*)(qp);
    qf[1] = *(const bf16x8*)(qp + 32);
  }

  float l_r = 0.f;
  f32x4 o_acc[4];
  const f32x4 zero = {0.f, 0.f, 0.f, 0.f};
#pragma unroll
  for (int n = 0; n < 4; ++n) o_acc[n] = zero;

  bf16_t* P = &Pls[w][0];

  stage_k128(Kg, Kls, 0, w, l);
  stage_v128(Vg, Vls, 0, w, l);
  WAITVM(0);
  __builtin_amdgcn_s_barrier();

  for (int tg = 0; tg < NT; ++tg) {
    const int tloc = (tg < nA) ? tg : tg - nA;
    const int kv0 = tloc * 128;
    const bool more = (tg + 1 < NT);
    const bool diag = (tloc == nTc - 1);
    const bool skip2 = diag && ((qt & 1) == 0);
    // next tile's kv0 (chain-aware)
    const int ntloc = (tg + 1 < nA) ? (tg + 1) : (tg + 1 - nA);
    const int nkv0 = ntloc * 128;

    f32x4 sf[8];
    auto qk_n = [&](int n) {
      const int kvc = n * 16 + r15;
      const int sw = kvc & 7;
      bf16x8 kf0 = *(const bf16x8*)(Kls + kvc * 64 + ((lh ^ sw) * 8));
      bf16x8 kf1 = *(const bf16x8*)(Kls + kvc * 64 + (((4 + lh) ^ sw) * 8));
      f32x4 a = zero;
      a = __builtin_amdgcn_mfma_f32_16x16x32_bf16(kf0, qf[0], a, 0, 0, 0);
      a = __builtin_amdgcn_mfma_f32_16x16x32_bf16(kf1, qf[1], a, 0, 0, 0);
      sf[n] = a;
    };
    __builtin_amdgcn_s_setprio(1);
#pragma unroll
    for (int n = 0; n < 4; ++n) qk_n(n);
    __builtin_amdgcn_s_setprio(0);
    if (!skip2) {
      __builtin_amdgcn_s_setprio(1);
#pragma unroll
      for (int n = 4; n < 8; ++n) qk_n(n);
      __builtin_amdgcn_s_setprio(0);
    }

    WAITVM(0);
    __builtin_amdgcn_s_barrier();
    if (more) stage_k128(Kg, Kls, nkv0, w, l);

    auto sm_half = [&](int hh, bool dm) {
#pragma unroll
      for (int n2 = 0; n2 < 4; ++n2) {
        const int n = hh * 4 + n2;
        float pv[4];
#pragma unroll
        for (int j = 0; j < 4; ++j) {
          float pp = fast_exp2(sf[n][j]);
          if (dm) {
            const int kvcol = kv0 + hh * 64 + n2 * 16 + lh * 4 + j;
            if (kvcol > qrow) pp = 0.f;
          }
          pv[j] = pp;
          l_r += pp;
        }
        bf16x4 pk = { (bf16_t)pv[0], (bf16_t)pv[1], (bf16_t)pv[2], (bf16_t)pv[3] };
        const int slot = n2 * 2 + (lh >> 1);
        *(bf16x4*)(P + r15 * 64 + ((slot ^ sw7) * 8) + (lh & 1) * 4) = pk;
      }
    };
    auto pv_half = [&](int hh) {
      bf16x8 pa0 = *(const bf16x8*)(P + r15 * 64 + ((lh ^ sw7) * 8));
      bf16x8 pa1 = *(const bf16x8*)(P + r15 * 64 + (((4 + lh) ^ sw7) * 8));
      __builtin_amdgcn_s_setprio(1);
#pragma unroll
      for (int nD = 0; nD < 4; ++nD) {
        const int d = nD * 16 + r15;
        const int b0 = (hh * 8 + lh) ^ r15;
        const int b1 = (hh * 8 + 4 + lh) ^ r15;
        bf16x8 vf0 = *(const bf16x8*)(Vls + d * 128 + b0 * 8);
        bf16x8 vf1 = *(const bf16x8*)(Vls + d * 128 + b1 * 8);
        o_acc[nD] = __builtin_amdgcn_mfma_f32_16x16x32_bf16(vf0, pa0, o_acc[nD], 0, 0, 0);
        o_acc[nD] = __builtin_amdgcn_mfma_f32_16x16x32_bf16(vf1, pa1, o_acc[nD], 0, 0, 0);
      }
      __builtin_amdgcn_s_setprio(0);
    };

    sm_half(0, diag);
    pv_half(0);
    if (!skip2) {
      sm_half(1, diag);
      pv_half(1);
    }

    WAITVM(0);
    __builtin_amdgcn_s_barrier();
    if (more) stage_v128(Vg, Vls, nkv0, w, l);

    if (diag) {
      // chain epilogue: write O for current qt; switch to qtB if first chain
      float ls = l_r;
      ls += __shfl_xor(ls, 16, 64);
      ls += __shfl_xor(ls, 32, 64);
      const float invl = 1.f / ls;
      bf16_t* orow = Om + (size_t)(b * T_SEQ + qrow) * D_MODEL + h * 64;
#pragma unroll
      for (int n = 0; n < 4; ++n) {
        bf16x4 pk = { (bf16_t)(o_acc[n][0] * invl), (bf16_t)(o_acc[n][1] * invl),
                      (bf16_t)(o_acc[n][2] * invl), (bf16_t)(o_acc[n][3] * invl) };
        *(bf16x4*)(orow + n * 16 + lh * 4) = pk;
      }
      if (tg + 1 < NT) {
        qt = qtB;
        nTc = (qtB >> 1) + 1;
        qw = qt * 64 + w * 16;
        qrow = qw + r15;
        const bf16_t* qp = Qm + baseQ + (size_t)qrow * D_MODEL + lh * 8;
        qf[0] = *(const bf16x8*)(qp);
        qf[1] = *(const bf16x8*)(qp + 32);
        l_r = 0.f;
#pragma unroll
        for (int n = 0; n < 4; ++n) o_acc[n] = zero;
      }
    }
  }
}

// ---------------- host launch ----------------
extern "C" void kernel_launch(void* const* d_in, const int* in_sizes, int n_in,
                              void* d_out, int out_size, void* d_ws, size_t ws_size,
                              hipStream_t stream) {
  const float* x  = (const float*)d_in[0];
  const float* wq = (const float*)d_in[1];
  const float* bq = (const float*)d_in[2];
  const float* wk = (const float*)d_in[3];
  const float* bk = (const float*)d_in[4];
  const float* wv = (const float*)d_in[5];
  const float* bv = (const float*)d_in[6];
  const float* wo = (const float*)d_in[7];
  const float* bo = (const float*)d_in[8];

  char* ws = (char*)d_ws;
  const size_t MB = 1024 * 1024;
  bf16_t* xb  = (bf16_t*)(ws);
  bf16_t* wqb = (bf16_t*)(ws + 8 * MB);
  bf16_t* wkb = (bf16_t*)(ws + 10 * MB);
  bf16_t* wvb = (bf16_t*)(ws + 12 * MB);
  bf16_t* wob = (bf16_t*)(ws + 14 * MB);
  bf16_t* qb  = (bf16_t*)(ws + 16 * MB);
  bf16_t* kb  = (bf16_t*)(ws + 24 * MB);
  bf16_t* vtb = (bf16_t*)(ws + 32 * MB);  // V^T [B][1024][2048]
  bf16_t* ob  = (bf16_t*)(ws + 40 * MB);

  CastArgs ca;
  ca.src[0] = x;  ca.dst[0] = xb;
  ca.src[1] = wq; ca.dst[1] = wqb;
  ca.src[2] = wk; ca.dst[2] = wkb;
  ca.src[3] = wv; ca.dst[3] = wvb;
  ca.src[4] = wo; ca.dst[4] = wob;
  cast_all<<<4096, 256, 0, stream>>>(ca);

  QKVArgs qa;
  qa.A = xb;
  qa.W[0] = wqb; qa.W[1] = wkb; qa.W[2] = wvb;
  qa.bias[0] = bq; qa.bias[1] = bk; qa.bias[2] = bv;
  qa.out[0] = qb; qa.out[1] = kb; qa.out[2] = vtb;
  qkv_gemm<<<512, 256, 0, stream>>>(qa);

  flash_attn<<<512, 256, 0, stream>>>(qb, kb, vtb, ob);

  out_gemm<<<dim3(64, 8), 256, 0, stream>>>(ob, wob, bo, (float*)d_out);
}

// Round 17
// 88.835 us; speedup vs baseline: 1.0610x; 1.0610x over previous
//
#include <hip/hip_runtime.h>
#include <hip/hip_bf16.h>

typedef __bf16 bf16_t;
typedef __bf16 bf16x8 __attribute__((ext_vector_type(8)));
typedef __bf16 bf16x4 __attribute__((ext_vector_type(4)));
typedef float f32x4 __attribute__((ext_vector_type(4)));
typedef unsigned int u32;

#define D_MODEL 1024
#define T_SEQ   2048
#define N_HEADS 16

#define WAITVM(N) asm volatile("s_waitcnt vmcnt(" #N ")" ::: "memory")

__device__ __forceinline__ void gload_lds16(const void* g, void* l) {
  __builtin_amdgcn_global_load_lds((const __attribute__((address_space(1))) u32*)g,
                                   (__attribute__((address_space(3))) u32*)l, 16, 0, 0);
}

__device__ __forceinline__ float fast_exp2(float x) {
#if __has_builtin(__builtin_amdgcn_exp2f)
  return __builtin_amdgcn_exp2f(x);
#else
  return __expf(x * 0.69314718056f);
#endif
}

// ---------------- fused fp32->bf16 cast (x + 4 weights), 8 elems/thread ------
struct CastArgs { const float* src[5]; bf16_t* dst[5]; };

__global__ __launch_bounds__(256) void cast_all(CastArgs p) {
  unsigned i = (blockIdx.x * 256u + threadIdx.x) * 8u;
  int seg; unsigned off;
  if (i < 4194304u) { seg = 0; off = i; }
  else { unsigned r = i - 4194304u; seg = 1 + (int)(r >> 20); off = r & 1048575u; }
  const float4 v0 = *(const float4*)(p.src[seg] + off);
  const float4 v1 = *(const float4*)(p.src[seg] + off + 4);
  bf16x8 o = { (bf16_t)v0.x, (bf16_t)v0.y, (bf16_t)v0.z, (bf16_t)v0.w,
               (bf16_t)v1.x, (bf16_t)v1.y, (bf16_t)v1.z, (bf16_t)v1.w };
  *(bf16x8*)(p.dst[seg] + off) = o;
}

#define QSCL 0.18033688011112042f   // 0.125 * log2(e)

// ============== fused QKV: 128x192 tile, BK=64, 256 thr, 2 blocks/CU =========
struct QKVArgs {
  const bf16_t* A;
  const bf16_t* W[3];
  const float* bias[3];
  bf16_t* out[3];
};

__global__ __launch_bounds__(256, 2) void qkv_gemm(QKVArgs p) {
  __shared__ bf16_t lds[2 * 20480];   // [buf][A:8192 | B:12288] elems

  const int tid = threadIdx.x;
  const int l = tid & 63, w = tid >> 6;
  const int lh = l >> 4, r15 = l & 15;

  const int lid = blockIdx.x;
  const int by = lid & 15, bx = lid >> 4;
  const int brow = bx * 128;
  const int gcol0 = by * 192;

  const int wr = (w >> 1) * 64;
  const int wc = (w & 1) * 96;
  const int wrc = wr >> 4;
  const int wcc = wc >> 4;
  const int sA = (lh ^ ((r15 >> 1) & 3)) * 8;
  const int roff = r15 * 32;

  const int srow = l >> 2;
  const int gs = ((l & 3) ^ ((l >> 3) & 3)) * 8;

  f32x4 acc[4][6];
  const f32x4 zero = {0.f, 0.f, 0.f, 0.f};
#pragma unroll
  for (int i = 0; i < 4; ++i)
#pragma unroll
    for (int j = 0; j < 6; ++j) acc[i][j] = zero;

  const bf16_t* A = p.A;

  auto stage = [&](bf16_t* buf, int k0) {
#pragma unroll
    for (int i = 0; i < 4; ++i) {
      int c = w * 4 + i;
      int kh = c >> 3, cc = c & 7;
      gload_lds16(A + (size_t)(brow + cc * 16 + srow) * D_MODEL + k0 + kh * 32 + gs,
                  buf + c * 512);
    }
#pragma unroll
    for (int i = 0; i < 6; ++i) {
      int g = w * 6 + i;
      int kh = g >= 12;
      int cb = g - kh * 12;
      int gcol = gcol0 + cb * 16 + srow;
      int z = gcol >> 10;
      const bf16_t* wt = (z == 0) ? p.W[0] : ((z == 1) ? p.W[1] : p.W[2]);
      gload_lds16(wt + (size_t)(gcol & 1023) * D_MODEL + k0 + kh * 32 + gs,
                  buf + 8192 + g * 512);
    }
  };

  stage(lds, 0);

  for (int t = 0; t < 16; ++t) {
    bf16_t* cur = lds + (t & 1) * 20480;
    WAITVM(0);
    __builtin_amdgcn_s_barrier();
    if (t < 15) stage(lds + ((t + 1) & 1) * 20480, (t + 1) * 64);

#pragma unroll
    for (int kh = 0; kh < 2; ++kh) {
      bf16x8 bfr[6];
#pragma unroll
      for (int ni = 0; ni < 6; ++ni)
        bfr[ni] = *(const bf16x8*)(cur + 8192 + (kh * 12 + wcc + ni) * 512 + roff + sA);
      __builtin_amdgcn_s_setprio(1);
#pragma unroll
      for (int mi = 0; mi < 4; ++mi) {
        bf16x8 af = *(const bf16x8*)(cur + (kh * 8 + wrc + mi) * 512 + roff + sA);
#pragma unroll
        for (int ni = 0; ni < 6; ++ni)
          acc[mi][ni] = __builtin_amdgcn_mfma_f32_16x16x32_bf16(af, bfr[ni], acc[mi][ni], 0, 0, 0);
      }
      __builtin_amdgcn_s_setprio(0);
    }
  }

#pragma unroll
  for (int ni = 0; ni < 6; ++ni) {
    const int col = gcol0 + wc + ni * 16 + r15;
    const int z = col >> 10;
    const int zc = col & 1023;
    const float* bias = (z == 0) ? p.bias[0] : ((z == 1) ? p.bias[1] : p.bias[2]);
    bf16_t* O = (z == 0) ? p.out[0] : ((z == 1) ? p.out[1] : p.out[2]);
    const float bz = bias[zc];
    if (z == 2) {
#pragma unroll
      for (int mi = 0; mi < 4; ++mi) {
        int row0 = brow + wr + mi * 16 + lh * 4;
        int bb = row0 >> 11, t0 = row0 & 2047;
        bf16x4 pk;
#pragma unroll
        for (int j = 0; j < 4; ++j) pk[j] = (bf16_t)(acc[mi][ni][j] + bz);
        *(bf16x4*)(O + (size_t)bb * (D_MODEL * T_SEQ) + (size_t)zc * T_SEQ + t0) = pk;
      }
    } else if (z == 0) {
#pragma unroll
      for (int mi = 0; mi < 4; ++mi) {
        int row0 = brow + wr + mi * 16 + lh * 4;
#pragma unroll
        for (int j = 0; j < 4; ++j)
          O[(size_t)(row0 + j) * D_MODEL + zc] = (bf16_t)((acc[mi][ni][j] + bz) * QSCL);
      }
    } else {
#pragma unroll
      for (int mi = 0; mi < 4; ++mi) {
        int row0 = brow + wr + mi * 16 + lh * 4;
#pragma unroll
        for (int j = 0; j < 4; ++j)
          O[(size_t)(row0 + j) * D_MODEL + zc] = (bf16_t)(acc[mi][ni][j] + bz);
      }
    }
  }
}

// ---------------- out projection: 64x128 tile, R14 handshake ----------------
__global__ __launch_bounds__(256, 2) void out_gemm(
    const bf16_t* __restrict__ A, const bf16_t* __restrict__ W,
    const float* __restrict__ bias, float* __restrict__ O)
{
  __shared__ bf16_t lds[2 * 12288];

  const int tid = threadIdx.x;
  const int l = tid & 63, w = tid >> 6;
  const int lh = l >> 4, r15 = l & 15;

  const int brow = blockIdx.x * 64, bcol = blockIdx.y * 128;
  const int wr = (w >> 1) * 32;
  const int wc = (w & 1) * 64;
  const int wrc = wr >> 4;
  const int wcc = wc >> 4;
  const int sA = (lh ^ ((r15 >> 1) & 3)) * 8;
  const int roff = r15 * 32;

  const int srow = l >> 2;
  const int gs = ((l & 3) ^ ((l >> 3) & 3)) * 8;

  f32x4 acc[2][4];
  const f32x4 zero = {0.f, 0.f, 0.f, 0.f};
#pragma unroll
  for (int i = 0; i < 2; ++i)
#pragma unroll
    for (int j = 0; j < 4; ++j) acc[i][j] = zero;

  auto stage = [&](bf16_t* buf, int k0) {
#pragma unroll
    for (int i = 0; i < 2; ++i) {
      int c = w * 2 + i;
      int kh = c >> 2, cc = c & 3;
      gload_lds16(A + (size_t)(brow + cc * 16 + srow) * D_MODEL + k0 + kh * 32 + gs,
                  buf + c * 512);
    }
#pragma unroll
    for (int i = 0; i < 4; ++i) {
      int g = w * 4 + i;
      int kh = g >> 3, cb = g & 7;
      gload_lds16(W + (size_t)(bcol + cb * 16 + srow) * D_MODEL + k0 + kh * 32 + gs,
                  buf + 4096 + g * 512);
    }
  };

  stage(lds, 0);

  for (int t = 0; t < 16; ++t) {
    bf16_t* cur = lds + (t & 1) * 12288;
    WAITVM(0);
    __builtin_amdgcn_s_barrier();
    if (t < 15) stage(lds + ((t + 1) & 1) * 12288, (t + 1) * 64);

#pragma unroll
    for (int kh = 0; kh < 2; ++kh) {
      bf16x8 bfr[4];
#pragma unroll
      for (int ni = 0; ni < 4; ++ni)
        bfr[ni] = *(const bf16x8*)(cur + 4096 + (kh * 8 + wcc + ni) * 512 + roff + sA);
      __builtin_amdgcn_s_setprio(1);
#pragma unroll
      for (int mi = 0; mi < 2; ++mi) {
        bf16x8 af = *(const bf16x8*)(cur + (kh * 4 + wrc + mi) * 512 + roff + sA);
#pragma unroll
        for (int ni = 0; ni < 4; ++ni)
          acc[mi][ni] = __builtin_amdgcn_mfma_f32_16x16x32_bf16(af, bfr[ni], acc[mi][ni], 0, 0, 0);
      }
      __builtin_amdgcn_s_setprio(0);
    }
  }

#pragma unroll
  for (int ni = 0; ni < 4; ++ni) {
    int col = bcol + wc + ni * 16 + r15;
    float bz = bias[col];
#pragma unroll
    for (int mi = 0; mi < 2; ++mi) {
      int row0 = brow + wr + mi * 16 + lh * 4;
#pragma unroll
      for (int j = 0; j < 4; ++j)
        O[(size_t)(row0 + j) * D_MODEL + col] = acc[mi][ni][j] + bz;
    }
  }
}

// ---------------- causal flash attention: balanced, KVBLK=128, 40KB LDS ------
// 1024 blocks: g = lid>>5 -> (r = g>>3, s = g&7) -> qt table {31-s,16+s,15-s,s}
// gives every CU slot exactly 34 tile-units (LPT: big qt dispatch first).
// bh = lid&31 (head pinned to one XCD). Body = R13 proven handshake.
__device__ __forceinline__ void stage_k128(const bf16_t* Kg, bf16_t* Kd, int kv0, int w, int l) {
#pragma unroll
  for (int i = 0; i < 4; ++i) {
    int c = w * 4 + i;
    int row = c * 8 + (l >> 3);
    int gcol = ((l & 7) ^ ((l >> 3) & 7)) * 8;
    gload_lds16(Kg + (size_t)(kv0 + row) * D_MODEL + gcol, Kd + c * 512);
  }
}
__device__ __forceinline__ void stage_v128(const bf16_t* Vg, bf16_t* Vd, int kv0, int w, int l) {
#pragma unroll
  for (int i = 0; i < 4; ++i) {
    int c = w * 4 + i;
    int drow = c * 4 + (l >> 4);
    int gkv = ((l & 15) ^ (drow & 15)) * 8;
    gload_lds16(Vg + (size_t)drow * T_SEQ + kv0 + gkv, Vd + c * 512);
  }
}

__global__ __launch_bounds__(256) void flash_attn(
    const bf16_t* __restrict__ Qm, const bf16_t* __restrict__ Km,
    const bf16_t* __restrict__ Vtg, bf16_t* __restrict__ Om)
{
  __shared__ bf16_t Kls[128 * 64];
  __shared__ bf16_t Vls[64 * 128];
  __shared__ bf16_t Pls[4][16 * 64];

  const int tid = threadIdx.x, l = tid & 63, w = tid >> 6;
  const int lh = l >> 4, r15 = l & 15;

  const int lid = blockIdx.x;
  const int g = lid >> 5;
  const int r = g >> 3, s = g & 7;
  const int qt = (r == 0) ? (31 - s) : ((r == 1) ? (16 + s) : ((r == 2) ? (15 - s) : s));
  const int bh = lid & 31;
  const int b = bh >> 4, h = bh & 15;
  const int nT = (qt >> 1) + 1;

  const size_t baseQ = (size_t)b * T_SEQ * D_MODEL + h * 64;
  const size_t baseVt = (size_t)b * (D_MODEL * T_SEQ) + (size_t)(h * 64) * T_SEQ;
  const bf16_t* Kg = Km + baseQ;
  const bf16_t* Vg = Vtg + baseVt;

  const int qw = qt * 64 + w * 16;
  const int qrow = qw + r15;
  const int sw7 = r15 & 7;

  bf16x8 qf[2];
  {
    const bf16_t* qp = Qm + baseQ + (size_t)qrow * D_MODEL + lh * 8;
    qf[0] = *(const bf16x8*)(qp);
    qf[1] = *(const bf16x8*)(qp + 32);
  }

  float l_r = 0.f;
  f32x4 o_acc[4];
  const f32x4 zero = {0.f, 0.f, 0.f, 0.f};
#pragma unroll
  for (int n = 0; n < 4; ++n) o_acc[n] = zero;

  bf16_t* P = &Pls[w][0];

  stage_k128(Kg, Kls, 0, w, l);
  stage_v128(Vg, Vls, 0, w, l);
  WAITVM(0);
  __builtin_amdgcn_s_barrier();

  for (int t = 0; t < nT; ++t) {
    const int kv0 = t * 128;
    const bool more = (t + 1 < nT);
    const bool diag = (t == nT - 1);
    const bool skip2 = diag && ((qt & 1) == 0);
    // exact mask analysis: for odd qt the diag tile's lower half is fully
    // unmasked (kv < qt*64 <= qrow); for even qt the upper half is fully
    // masked (skip2) and the lower half needs the mask.
    const bool dm0 = diag && ((qt & 1) == 0);

    f32x4 sf[8];
    auto qk_n = [&](int n) {
      const int kvc = n * 16 + r15;
      const int sw = kvc & 7;
      bf16x8 kf0 = *(const bf16x8*)(Kls + kvc * 64 + ((lh ^ sw) * 8));
      bf16x8 kf1 = *(const bf16x8*)(Kls + kvc * 64 + (((4 + lh) ^ sw) * 8));
      f32x4 a = zero;
      a = __builtin_amdgcn_mfma_f32_16x16x32_bf16(kf0, qf[0], a, 0, 0, 0);
      a = __builtin_amdgcn_mfma_f32_16x16x32_bf16(kf1, qf[1], a, 0, 0, 0);
      sf[n] = a;
    };
    __builtin_amdgcn_s_setprio(1);
#pragma unroll
    for (int n = 0; n < 4; ++n) qk_n(n);
    __builtin_amdgcn_s_setprio(0);
    if (!skip2) {
      __builtin_amdgcn_s_setprio(1);
#pragma unroll
      for (int n = 4; n < 8; ++n) qk_n(n);
      __builtin_amdgcn_s_setprio(0);
    }

    WAITVM(0);
    __builtin_amdgcn_s_barrier();
    if (more) stage_k128(Kg, Kls, kv0 + 128, w, l);

    auto sm_half = [&](int hh, bool dm) {
#pragma unroll
      for (int n2 = 0; n2 < 4; ++n2) {
        const int n = hh * 4 + n2;
        float pv[4];
#pragma unroll
        for (int j = 0; j < 4; ++j) {
          float pp = fast_exp2(sf[n][j]);
          if (dm) {
            const int kvcol = kv0 + hh * 64 + n2 * 16 + lh * 4 + j;
            if (kvcol > qrow) pp = 0.f;
          }
          pv[j] = pp;
        }
        l_r += (pv[0] + pv[1]) + (pv[2] + pv[3]);   // pairwise: short dep chain
        bf16x4 pk = { (bf16_t)pv[0], (bf16_t)pv[1], (bf16_t)pv[2], (bf16_t)pv[3] };
        const int slot = n2 * 2 + (lh >> 1);
        *(bf16x4*)(P + r15 * 64 + ((slot ^ sw7) * 8) + (lh & 1) * 4) = pk;
      }
    };
    auto pv_half = [&](int hh) {
      bf16x8 pa0 = *(const bf16x8*)(P + r15 * 64 + ((lh ^ sw7) * 8));
      bf16x8 pa1 = *(const bf16x8*)(P + r15 * 64 + (((4 + lh) ^ sw7) * 8));
      __builtin_amdgcn_s_setprio(1);
#pragma unroll
      for (int nD = 0; nD < 4; ++nD) {
        const int d = nD * 16 + r15;
        const int b0 = (hh * 8 + lh) ^ r15;
        const int b1 = (hh * 8 + 4 + lh) ^ r15;
        bf16x8 vf0 = *(const bf16x8*)(Vls + d * 128 + b0 * 8);
        bf16x8 vf1 = *(const bf16x8*)(Vls + d * 128 + b1 * 8);
        o_acc[nD] = __builtin_amdgcn_mfma_f32_16x16x32_bf16(vf0, pa0, o_acc[nD], 0, 0, 0);
        o_acc[nD] = __builtin_amdgcn_mfma_f32_16x16x32_bf16(vf1, pa1, o_acc[nD], 0, 0, 0);
      }
      __builtin_amdgcn_s_setprio(0);
    };

    sm_half(0, dm0);
    pv_half(0);
    if (!skip2) {
      sm_half(1, diag);     // executes only when qt odd on diag -> mask needed
      pv_half(1);
    }

    WAITVM(0);
    __builtin_amdgcn_s_barrier();
    if (more) stage_v128(Vg, Vls, kv0 + 128, w, l);
  }

  float ls = l_r;
  ls += __shfl_xor(ls, 16, 64);
  ls += __shfl_xor(ls, 32, 64);
  const float invl = 1.f / ls;
  bf16_t* orow = Om + (size_t)(b * T_SEQ + qrow) * D_MODEL + h * 64;
#pragma unroll
  for (int n = 0; n < 4; ++n) {
    bf16x4 pk = { (bf16_t)(o_acc[n][0] * invl), (bf16_t)(o_acc[n][1] * invl),
                  (bf16_t)(o_acc[n][2] * invl), (bf16_t)(o_acc[n][3] * invl) };
    *(bf16x4*)(orow + n * 16 + lh * 4) = pk;
  }
}

// ---------------- host launch ----------------
extern "C" void kernel_launch(void* const* d_in, const int* in_sizes, int n_in,
                              void* d_out, int out_size, void* d_ws, size_t ws_size,
                              hipStream_t stream) {
  const float* x  = (const float*)d_in[0];
  const float* wq = (const float*)d_in[1];
  const float* bq = (const float*)d_in[2];
  const float* wk = (const float*)d_in[3];
  const float* bk = (const float*)d_in[4];
  const float* wv = (const float*)d_in[5];
  const float* bv = (const float*)d_in[6];
  const float* wo = (const float*)d_in[7];
  const float* bo = (const float*)d_in[8];

  char* ws = (char*)d_ws;
  const size_t MB = 1024 * 1024;
  bf16_t* xb  = (bf16_t*)(ws);
  bf16_t* wqb = (bf16_t*)(ws + 8 * MB);
  bf16_t* wkb = (bf16_t*)(ws + 10 * MB);
  bf16_t* wvb = (bf16_t*)(ws + 12 * MB);
  bf16_t* wob = (bf16_t*)(ws + 14 * MB);
  bf16_t* qb  = (bf16_t*)(ws + 16 * MB);
  bf16_t* kb  = (bf16_t*)(ws + 24 * MB);
  bf16_t* vtb = (bf16_t*)(ws + 32 * MB);  // V^T [B][1024][2048]
  bf16_t* ob  = (bf16_t*)(ws + 40 * MB);

  CastArgs ca;
  ca.src[0] = x;  ca.dst[0] = xb;
  ca.src[1] = wq; ca.dst[1] = wqb;
  ca.src[2] = wk; ca.dst[2] = wkb;
  ca.src[3] = wv; ca.dst[3] = wvb;
  ca.src[4] = wo; ca.dst[4] = wob;
  cast_all<<<4096, 256, 0, stream>>>(ca);

  QKVArgs qa;
  qa.A = xb;
  qa.W[0] = wqb; qa.W[1] = wkb; qa.W[2] = wvb;
  qa.bias[0] = bq; qa.bias[1] = bk; qa.bias[2] = bv;
  qa.out[0] = qb; qa.out[1] = kb; qa.out[2] = vtb;
  qkv_gemm<<<512, 256, 0, stream>>>(qa);

  flash_attn<<<1024, 256, 0, stream>>>(qb, kb, vtb, ob);

  out_gemm<<<dim3(64, 8), 256, 0, stream>>>(ob, wob, bo, (float*)d_out);
}